// Round 1
// baseline (78.418 us; speedup 1.0000x reference)
//
#include <hip/hip_runtime.h>
#include <hip/hip_bf16.h>

namespace {

constexpr int B_N = 8;
constexpr int A_N = 100000;
constexpr int C_N = 8;
constexpr int M_N = 128;
constexpr int BLOCK = 256;
constexpr int NBLK = (A_N + BLOCK - 1) / BLOCK;  // 391

// ---------------------------------------------------------------------------
// Main kernel: one thread per anchor. grid = (NBLK, B).
// Computes per-block partial sums of {cls_loss_sum, reg_loss_sum, vp_loss_sum,
// pos_count} (unnormalized; num_pos division happens in reduce_img).
// ---------------------------------------------------------------------------
__global__ __launch_bounds__(BLOCK) void focal_main(
    const float* __restrict__ cls_,      // (B, A, C)
    const float* __restrict__ reg_,      // (B, A, 8)
    const float* __restrict__ anchors_,  // (1, A, 4)
    const float* __restrict__ ann_,      // (B, M, 18)
    float* __restrict__ partials)        // (B, NBLK, 4)
{
    __shared__ float  s_ann[M_N * 18];
    __shared__ float4 s_bb[M_N];    // x1, y1, x2, y2 of box2d
    __shared__ float4 s_meta[M_N];  // area, class, valid, pad

    const int b   = blockIdx.y;
    const int tid = threadIdx.x;

    // Stage this image's annotations (coalesced), then derive box2d per box.
    const float* annb = ann_ + (size_t)b * M_N * 18;
    for (int i = tid; i < M_N * 18; i += BLOCK) s_ann[i] = annb[i];
    __syncthreads();
    if (tid < M_N) {
        const float* t = s_ann + tid * 18;
        float minx = t[0], maxx = t[0], miny = t[1], maxy = t[1];
#pragma unroll
        for (int j = 1; j < 8; ++j) {
            minx = fminf(minx, t[2 * j]);     maxx = fmaxf(maxx, t[2 * j]);
            miny = fminf(miny, t[2 * j + 1]); maxy = fmaxf(maxy, t[2 * j + 1]);
        }
        s_bb[tid] = make_float4(minx, miny, maxx, maxy);
        const float area = (maxx - minx) * (maxy - miny);
        const float c    = t[17];
        s_meta[tid] = make_float4(area, c, (c >= 0.0f) ? 1.0f : 0.0f, 0.0f);
    }
    __syncthreads();

    const int a = blockIdx.x * BLOCK + tid;
    float clsS = 0.f, regS = 0.f, vpS = 0.f, posC = 0.f;

    if (a < A_N) {
        const float4 an   = ((const float4*)anchors_)[a];
        const float  aw   = an.z - an.x;
        const float  ah   = an.w - an.y;
        const float  acx  = an.x + 0.5f * aw;
        const float  acy  = an.y + 0.5f * ah;
        const float  aarea = aw * ah;

        // IoU argmax, division-free: iou_m > iou_best  <=>  inter_m*ua_best >
        // inter_best*ua_m (denominators clipped positive). Strict '>' keeps the
        // FIRST max index, matching jnp.argmax. Init (-1, 1) so any valid box
        // (iou >= 0 > -ua) wins; all-invalid leaves kbest=0 like the reference.
        float bn = -1.0f, bd = 1.0f;
        int   kbest = 0;
        for (int m = 0; m < M_N; ++m) {
            const float4 bb = s_bb[m];
            const float4 mt = s_meta[m];
            float iw = fminf(an.z, bb.z) - fmaxf(an.x, bb.x);
            float ih = fminf(an.w, bb.w) - fmaxf(an.y, bb.y);
            iw = fmaxf(iw, 0.0f);
            ih = fmaxf(ih, 0.0f);
            const float inter = iw * ih;
            const float ua    = fmaxf(aarea + mt.x - inter, 1e-8f);
            const bool  upd   = (mt.z > 0.0f) && (inter * bd > bn * ua);
            if (upd) { bn = inter; bd = ua; kbest = m; }
        }
        const float iou_max = (bn < 0.0f) ? -1.0f : bn / bd;
        const bool  pos = (iou_max >= 0.5f);
        const bool  neg = (iou_max <  0.4f);

        // ---- classification focal loss --------------------------------
        if (pos | neg) {
            const float* cp = cls_ + ((size_t)b * A_N + a) * C_N;
            const float4 c0 = ((const float4*)cp)[0];
            const float4 c1 = ((const float4*)cp)[1];
            const float pv[8] = {c0.x, c0.y, c0.z, c0.w, c1.x, c1.y, c1.z, c1.w};
            const int kc = pos ? (int)s_meta[kbest].y : -1;
            float sneg = 0.f, pkc = 0.5f, negkc = 0.f;
#pragma unroll
            for (int c = 0; c < C_N; ++c) {
                const float pc   = fminf(fmaxf(pv[c], 1e-4f), 1.0f - 1e-4f);
                const float term = 0.75f * pc * pc * (-__logf(1.0f - pc));
                sneg += term;
                if (c == kc) { pkc = pc; negkc = term; }  // unrolled selects, no dyn idx
            }
            clsS = pos ? (sneg - negkc +
                          0.25f * (1.0f - pkc) * (1.0f - pkc) * (-__logf(pkc)))
                       : sneg;
        }

        // ---- regression + vp losses (pos anchors only) ----------------
        if (pos) {
            posC = 1.0f;
            const float* rp = reg_ + ((size_t)b * A_N + a) * 8;
            const float4 r0 = ((const float4*)rp)[0];  // reg0..3
            const float4 r1 = ((const float4*)rp)[1];  // reg4..7
            const float* t  = s_ann + kbest * 18;
            float tt[16];
#pragma unroll
            for (int j = 0; j < 16; ++j) tt[j] = t[j];

            auto vp = [](float rx, float ry, float tx, float ty) {
                const float denom = sqrtf(rx * rx + ry * ry) * sqrtf(tx * tx + ty * ty);
                return 1.0f - (rx * tx + ry * ty) / fmaxf(denom, 1e-8f);
            };
            const float vp1 = vp(r0.z, r0.w,
                (tt[4] + tt[6] + tt[12] + tt[14] - (tt[0] + tt[2] + tt[8] + tt[10])) * 0.25f,
                (tt[5] + tt[7] + tt[13] + tt[15] - (tt[1] + tt[3] + tt[9] + tt[11])) * 0.25f);
            const float vp2 = vp(r1.x, r1.y,
                (tt[2] + tt[6] + tt[10] + tt[14] - (tt[0] + tt[4] + tt[8] + tt[12])) * 0.25f,
                (tt[3] + tt[7] + tt[11] + tt[15] - (tt[1] + tt[5] + tt[9] + tt[13])) * 0.25f);
            const float vp3 = vp(r1.z, r1.w,
                (tt[0] + tt[2] + tt[4] + tt[6] - (tt[8] + tt[10] + tt[12] + tt[14])) * 0.25f,
                (tt[1] + tt[3] + tt[5] + tt[7] - (tt[9] + tt[11] + tt[13] + tt[15])) * 0.25f);
            vpS = (vp1 + vp2 + vp3) * (1.0f / 3.0f);

            const float s2[8] = {-1, -1, 1, 1, -1, -1, 1, 1};
            const float s4[8] = {-1, 1, -1, 1, -1, 1, -1, 1};
            const float s6[8] = {1, 1, 1, 1, -1, -1, -1, -1};
            float ssum = 0.f;
#pragma unroll
            for (int j = 0; j < 8; ++j) {
                const float px = r0.x + r0.z * s2[j] + r1.x * s4[j] + r1.z * s6[j];
                const float py = r0.y + r0.w * s2[j] + r1.y * s4[j] + r1.w * s6[j];
                const float tx = (tt[2 * j]     - acx) / aw;
                const float ty = (tt[2 * j + 1] - acy) / ah;
                const float dx = fabsf(px - tx);
                const float dy = fabsf(py - ty);
                ssum += (dx <= (1.0f / 9.0f)) ? 4.5f * dx * dx : dx - (0.5f / 9.0f);
                ssum += (dy <= (1.0f / 9.0f)) ? 4.5f * dy * dy : dy - (0.5f / 9.0f);
            }
            regS = ssum * (1.0f / 16.0f);
        }
    }

    // ---- block reduction (deterministic) ------------------------------
#pragma unroll
    for (int off = 32; off; off >>= 1) {
        clsS += __shfl_down(clsS, off);
        regS += __shfl_down(regS, off);
        vpS  += __shfl_down(vpS, off);
        posC += __shfl_down(posC, off);
    }
    __shared__ float s_red[4][4];
    const int wv = tid >> 6, ln = tid & 63;
    if (ln == 0) {
        s_red[wv][0] = clsS; s_red[wv][1] = regS;
        s_red[wv][2] = vpS;  s_red[wv][3] = posC;
    }
    __syncthreads();
    if (tid == 0) {
        float C = 0, R = 0, V = 0, P = 0;
        for (int w = 0; w < 4; ++w) {
            C += s_red[w][0]; R += s_red[w][1];
            V += s_red[w][2]; P += s_red[w][3];
        }
        float* out = partials + ((size_t)b * NBLK + blockIdx.x) * 4;
        out[0] = C; out[1] = R; out[2] = V; out[3] = P;
    }
}

// ---------------------------------------------------------------------------
// Per-image reduce + normalize. grid = B blocks.
// ---------------------------------------------------------------------------
__global__ __launch_bounds__(BLOCK) void reduce_img(
    const float* __restrict__ partials,  // (B, NBLK, 4)
    float* __restrict__ imgloss)         // (B, 3)
{
    const int b = blockIdx.x, tid = threadIdx.x;
    float c = 0.f, r = 0.f, v = 0.f, p = 0.f;
    for (int i = tid; i < NBLK; i += BLOCK) {
        const float* q = partials + ((size_t)b * NBLK + i) * 4;
        c += q[0]; r += q[1]; v += q[2]; p += q[3];
    }
#pragma unroll
    for (int off = 32; off; off >>= 1) {
        c += __shfl_down(c, off); r += __shfl_down(r, off);
        v += __shfl_down(v, off); p += __shfl_down(p, off);
    }
    __shared__ float s[4][4];
    const int wv = tid >> 6, ln = tid & 63;
    if (ln == 0) { s[wv][0] = c; s[wv][1] = r; s[wv][2] = v; s[wv][3] = p; }
    __syncthreads();
    if (tid == 0) {
        float C = 0, R = 0, V = 0, P = 0;
        for (int w = 0; w < 4; ++w) {
            C += s[w][0]; R += s[w][1]; V += s[w][2]; P += s[w][3];
        }
        const float np_ = fmaxf(P, 1.0f);
        imgloss[b * 3 + 0] = C / np_;
        imgloss[b * 3 + 1] = R / np_;
        imgloss[b * 3 + 2] = V / np_;
    }
}

// ---------------------------------------------------------------------------
// Final average over images. out[k] = mean_b imgloss[b][k].
// ---------------------------------------------------------------------------
__global__ void final_avg(const float* __restrict__ imgloss,
                          float* __restrict__ out)
{
    const int k = threadIdx.x;
    if (k < 3) {
        float s = 0.f;
        for (int b = 0; b < B_N; ++b) s += imgloss[b * 3 + k];
        out[k] = s * 0.125f;
    }
}

}  // namespace

extern "C" void kernel_launch(void* const* d_in, const int* in_sizes, int n_in,
                              void* d_out, int out_size, void* d_ws, size_t ws_size,
                              hipStream_t stream)
{
    const float* cls_    = (const float*)d_in[0];  // classifications (B,A,C)
    const float* reg_    = (const float*)d_in[1];  // regressions (B,A,8)
    const float* anchors = (const float*)d_in[2];  // anchors (1,A,4)
    const float* ann     = (const float*)d_in[3];  // annotations (B,M,18)
    // d_in[4] = embeddings: unused by the reference.

    float* partials = (float*)d_ws;                      // B*NBLK*4 floats
    float* imgloss  = partials + (size_t)B_N * NBLK * 4; // B*3 floats

    dim3 grid(NBLK, B_N);
    focal_main<<<grid, dim3(BLOCK), 0, stream>>>(cls_, reg_, anchors, ann, partials);
    reduce_img<<<dim3(B_N), dim3(BLOCK), 0, stream>>>(partials, imgloss);
    final_avg<<<dim3(1), dim3(64), 0, stream>>>(imgloss, (float*)d_out);
}